// Round 3
// baseline (1614.226 us; speedup 1.0000x reference)
//
#include <hip/hip_runtime.h>
#include <hip/hip_bf16.h>

// ---------------------------------------------------------------------------
// GINEConv x2 + mean-pool + 3 heads.  f32 pipeline (correctness anchor).
// KEY FACTS: float inputs = f32, OUTPUT = f32.  Int width runtime-detected.
//
// R5: W float4 in LDS, 8 edges/wave, v_readlane broadcast (killed LDS-pipe
//     bound: 995 -> 423us).
// R6: occupancy push 37->41% only; dur 423->411.  Two rounds pinned at
//     ~410us regardless of occupancy => external wall.
// R7 (this round): the wall is ATOMIC THROUGHPUT.  WRITE_SIZE == exactly
//     102.4M atomics * 4B: every atomic resolves memory-side (8 XCD L2s
//     non-coherent), 249G atomics/s ~ 104/cycle device-wide.  Fix: build
//     CSR once (shared by both layers), then one wave per DST node
//     accumulates messages in registers and does a plain store.  Zero
//     atomics in the hot path; self-term x+aggr folded in (kills cvt4/copy).
// ---------------------------------------------------------------------------

typedef __bf16 bf16_t;

#define N_NODES   50000
#define N_EDGES   800000
#define N_GRAPHS  512
#define HID       128
#define EIN       64
#define SCAN_BLK  1024
#define NCHUNK    49            // ceil(50000/1024)

// broadcast lane l of v across the wave via v_readlane (no LDS traffic)
#define RL(v, l) __int_as_float(__builtin_amdgcn_readlane(__float_as_int(v), (l)))

__device__ __forceinline__ float ldf(const void* p, size_t i, int f32m) {
    return f32m ? ((const float*)p)[i] : (float)((const bf16_t*)p)[i];
}
__device__ __forceinline__ int ldi(const void* p, size_t i, int i64m) {
    return i64m ? (int)((const long long*)p)[i] : ((const int*)p)[i];
}

// flags[0]=1 if floats are f32; flags[1]=1 if ints are i64.
__global__ void k_detect(const unsigned short* __restrict__ xw,
                         const unsigned int*   __restrict__ eiw,
                         int* __restrict__ flags)
{
    if (threadIdx.x == 0 && blockIdx.x == 0) {
        int sane = 0;
        for (int i = 0; i < 256; ++i) {
            int e = (xw[i] >> 7) & 0xFF;
            if (e >= 100 && e <= 150) ++sane;    // bf16 N(0,1): ~256; f32: ~154
        }
        flags[0] = (sane < 220) ? 1 : 0;
        int nzhigh = 0;
        for (int i = 0; i < 256; ++i)
            if (eiw[2*i + 1] != 0) ++nzhigh;     // i64 ids < 2^32: high words 0
        flags[1] = (nzhigh == 0) ? 1 : 0;
    }
}

// ---------------- CSR build (once; shared by both edge layers) -------------
__global__ void k_hist(const void* __restrict__ ei, int* __restrict__ CNT,
                       const int* __restrict__ flags)
{
    const int i64m = flags[1];
    int e = blockIdx.x * 256 + threadIdx.x;      // grid sized exactly
    int d = ldi(ei, (size_t)N_EDGES + e, i64m);
    atomicAdd(&CNT[d], 1);
}

// chunk-local exclusive scan (Hillis-Steele in LDS) + per-chunk totals
__global__ __launch_bounds__(SCAN_BLK) void k_scanA(const int* __restrict__ CNT,
                                                    int* __restrict__ OFF,
                                                    int* __restrict__ PS)
{
    __shared__ int tmp[SCAN_BLK];
    const int t = threadIdx.x;
    const int i = blockIdx.x * SCAN_BLK + t;
    const int v = (i < N_NODES) ? CNT[i] : 0;
    tmp[t] = v;
    __syncthreads();
    for (int off = 1; off < SCAN_BLK; off <<= 1) {
        int u = (t >= off) ? tmp[t - off] : 0;
        __syncthreads();
        tmp[t] += u;
        __syncthreads();
    }
    if (i < N_NODES) OFF[i] = tmp[t] - v;        // chunk-local exclusive
    if (t == SCAN_BLK - 1) PS[blockIdx.x] = tmp[t];
}

// exclusive scan of the 49 chunk totals (single wave, shuffle scan)
__global__ void k_scanB(int* __restrict__ PS)
{
    const int lane = threadIdx.x;                // 64 threads
    const int v0 = (lane < NCHUNK) ? PS[lane] : 0;
    int v = v0;
#pragma unroll
    for (int off = 1; off < 64; off <<= 1) {
        int u = __shfl_up(v, off, 64);
        if (lane >= off) v += u;
    }
    if (lane < NCHUNK) PS[lane] = v - v0;        // exclusive
}

__global__ void k_scanC(int* __restrict__ OFF, const int* __restrict__ PS,
                        int* __restrict__ CUR)
{
    int i = blockIdx.x * 256 + threadIdx.x;
    if (i < N_NODES) {
        int o = OFF[i] + PS[i >> 10];
        OFF[i] = o;
        CUR[i] = o;
    }
}

__global__ void k_scatter(const void* __restrict__ ei, int* __restrict__ CUR,
                          int2* __restrict__ ES, const int* __restrict__ flags)
{
    const int i64m = flags[1];
    int e = blockIdx.x * 256 + threadIdx.x;      // grid sized exactly
    int s = ldi(ei, e, i64m);
    int d = ldi(ei, (size_t)N_EDGES + e, i64m);
    int p = atomicAdd(&CUR[d], 1);
    ES[p] = make_int2(e, s);
}

// ---------------------------------------------------------------------------
// CSR edge layer: one wave per dst node.  out[n] = x[n] + sum over incoming
// edges of relu(x[src] + ea[e]@W + eb).  Plain store, ZERO atomics.
// Edges processed in chunks of 8 (readlane broadcast, W float4 in LDS).
// 512 thr/block, 33KB LDS -> 4 blocks/CU.
// ---------------------------------------------------------------------------
__global__ __launch_bounds__(512) void k_edge_csr(
        const void* __restrict__ Xg, int xg_ws,   // xg_ws=1: Xg is f32 workspace
        const int2* __restrict__ ES,
        const int*  __restrict__ OFF,
        const int*  __restrict__ CNT,
        const void* __restrict__ ea,
        const void* __restrict__ ew,
        const void* __restrict__ eb,
        float*      __restrict__ out,
        const int*  __restrict__ flags)
{
    __shared__ float4 Wq[16 * 128];               // 32 KB
    __shared__ float  ebs[HID];
    const int f32m = flags[0];
    const int xgf  = xg_ws ? 1 : f32m;

    for (int i = threadIdx.x; i < 16 * 128; i += 512) {
        int k4 = i >> 7, c = i & 127;
        float4 w;
        w.x = ldf(ew, (size_t)(4*k4+0)*HID + c, f32m);
        w.y = ldf(ew, (size_t)(4*k4+1)*HID + c, f32m);
        w.z = ldf(ew, (size_t)(4*k4+2)*HID + c, f32m);
        w.w = ldf(ew, (size_t)(4*k4+3)*HID + c, f32m);
        Wq[i] = w;
    }
    for (int i = threadIdx.x; i < HID; i += 512) ebs[i] = ldf(eb, i, f32m);
    __syncthreads();

    const int lane = threadIdx.x & 63;
    const int wid  = (blockIdx.x * 512 + threadIdx.x) >> 6;
    const int nw   = gridDim.x * 8;
    const float eb0 = ebs[lane], eb1 = ebs[64 + lane];

    for (int n = wid; n < N_NODES; n += nw) {
        const int st = OFF[n];
        const int d  = CNT[n];
        float a0 = ldf(Xg, (size_t)n * HID + lane,      xgf);   // self term
        float a1 = ldf(Xg, (size_t)n * HID + 64 + lane, xgf);

        for (int base = 0; base < d; base += 8) {
            const int m = d - base;               // valid count (>=1), wave-uniform
            float av[8]; int src[8];
#pragma unroll
            for (int i = 0; i < 8; ++i) {
                int2 es = ES[st + base + ((i < m) ? i : 0)];    // safe index
                src[i] = es.y;
                av[i]  = ldf(ea, (size_t)es.x * EIN + lane, f32m);
            }
            float macc0[8], macc1[8];
#pragma unroll
            for (int i = 0; i < 8; ++i) { macc0[i] = 0.f; macc1[i] = 0.f; }

#pragma unroll 4
            for (int k4 = 0; k4 < 16; ++k4) {
                float4 w0 = Wq[k4 * 128 + lane];
                float4 w1 = Wq[k4 * 128 + 64 + lane];
#pragma unroll
                for (int i = 0; i < 8; ++i) {
                    float a0b = RL(av[i], 4*k4+0);
                    float a1b = RL(av[i], 4*k4+1);
                    float a2b = RL(av[i], 4*k4+2);
                    float a3b = RL(av[i], 4*k4+3);
                    macc0[i] = fmaf(a3b, w0.w, fmaf(a2b, w0.z, fmaf(a1b, w0.y, fmaf(a0b, w0.x, macc0[i]))));
                    macc1[i] = fmaf(a3b, w1.w, fmaf(a2b, w1.z, fmaf(a1b, w1.y, fmaf(a0b, w1.x, macc1[i]))));
                }
            }
#pragma unroll
            for (int i = 0; i < 8; ++i) {
                if (i < m) {                      // wave-uniform guard
                    float x0 = ldf(Xg, (size_t)src[i] * HID + lane,      xgf);
                    float x1 = ldf(Xg, (size_t)src[i] * HID + 64 + lane, xgf);
                    a0 += fmaxf(x0 + macc0[i] + eb0, 0.f);
                    a1 += fmaxf(x1 + macc1[i] + eb1, 0.f);
                }
            }
        }
        out[(size_t)n * HID + lane]      = a0;
        out[(size_t)n * HID + 64 + lane] = a1;
    }
}

// ---------------------------------------------------------------------------
// Node MLP: Out[n] = relu(A[n] @ W + b).  8 nodes per wave, W float4 in LDS.
// 1024 thr/block, 64KB LDS -> 2 blocks/CU = 32 waves/CU.
// In-place safe: all 8 rows consumed into registers before any write.
// ---------------------------------------------------------------------------
__global__ __launch_bounds__(1024) void k_mlp_s(
        const float* __restrict__ A,
        const void*  __restrict__ W,
        const void*  __restrict__ bias,
        float*       __restrict__ Out,
        const int*   __restrict__ flags)
{
    __shared__ float4 Wq[32 * 128];               // 64 KB
    const int f32m = flags[0];
    for (int i = threadIdx.x; i < 32 * 128; i += 1024) {
        int k4 = i >> 7, c = i & 127;
        float4 w;
        w.x = ldf(W, (size_t)(4*k4+0)*HID + c, f32m);
        w.y = ldf(W, (size_t)(4*k4+1)*HID + c, f32m);
        w.z = ldf(W, (size_t)(4*k4+2)*HID + c, f32m);
        w.w = ldf(W, (size_t)(4*k4+3)*HID + c, f32m);
        Wq[i] = w;
    }
    __syncthreads();

    const int lane = threadIdx.x & 63;
    const int wid  = (blockIdx.x * 1024 + threadIdx.x) >> 6;
    const int nw   = gridDim.x * 16;
    const float b0 = ldf(bias, lane,      f32m);
    const float b1 = ldf(bias, 64 + lane, f32m);
    const int ngrp = N_NODES / 8;                 // 6250 exact

    for (int g = wid; g < ngrp; g += nw) {
        const int n0 = g * 8;
        float alo[8], ahi[8], acc0[8], acc1[8];
#pragma unroll
        for (int i = 0; i < 8; ++i) {
            alo[i] = A[(size_t)(n0+i) * HID + lane];
            ahi[i] = A[(size_t)(n0+i) * HID + 64 + lane];
            acc0[i] = b0; acc1[i] = b1;
        }
#pragma unroll 4
        for (int k4 = 0; k4 < 16; ++k4) {
            float4 w0 = Wq[k4 * 128 + lane];
            float4 w1 = Wq[k4 * 128 + 64 + lane];
#pragma unroll
            for (int i = 0; i < 8; ++i) {
                float a0 = RL(alo[i], 4*k4+0);
                float a1 = RL(alo[i], 4*k4+1);
                float a2 = RL(alo[i], 4*k4+2);
                float a3 = RL(alo[i], 4*k4+3);
                acc0[i] = fmaf(a3, w0.w, fmaf(a2, w0.z, fmaf(a1, w0.y, fmaf(a0, w0.x, acc0[i]))));
                acc1[i] = fmaf(a3, w1.w, fmaf(a2, w1.z, fmaf(a1, w1.y, fmaf(a0, w1.x, acc1[i]))));
            }
        }
#pragma unroll 4
        for (int k4 = 16; k4 < 32; ++k4) {
            float4 w0 = Wq[k4 * 128 + lane];
            float4 w1 = Wq[k4 * 128 + 64 + lane];
#pragma unroll
            for (int i = 0; i < 8; ++i) {
                float a0 = RL(ahi[i], 4*k4+0 - 64);
                float a1 = RL(ahi[i], 4*k4+1 - 64);
                float a2 = RL(ahi[i], 4*k4+2 - 64);
                float a3 = RL(ahi[i], 4*k4+3 - 64);
                acc0[i] = fmaf(a3, w0.w, fmaf(a2, w0.z, fmaf(a1, w0.y, fmaf(a0, w0.x, acc0[i]))));
                acc1[i] = fmaf(a3, w1.w, fmaf(a2, w1.z, fmaf(a1, w1.y, fmaf(a0, w1.x, acc1[i]))));
            }
        }
#pragma unroll
        for (int i = 0; i < 8; ++i) {
            Out[(size_t)(n0+i) * HID + lane]      = fmaxf(acc0[i], 0.f);
            Out[(size_t)(n0+i) * HID + 64 + lane] = fmaxf(acc1[i], 0.f);
        }
    }
}

// ---------------------------------------------------------------------------
// Pool: batch is SORTED -> run-length accumulate, flush at boundaries.
// ---------------------------------------------------------------------------
__global__ void k_pool_s(const float* __restrict__ X, const void* __restrict__ batch,
                         float* __restrict__ GS, float* __restrict__ GC,
                         const int* __restrict__ flags)
{
    const int i64m = flags[1];
    const int c  = threadIdx.x;                   // 0..127
    const int n0 = blockIdx.x * 64;
    const int nend = (n0 + 64 < N_NODES) ? n0 + 64 : N_NODES;

    int bprev = ldi(batch, n0, i64m);
    float acc = 0.f;
    int   cnt = 0;
    for (int n = n0; n < nend; ++n) {
        int b = ldi(batch, n, i64m);
        if (b != bprev) {
            unsafeAtomicAdd(&GS[(size_t)bprev * HID + c], acc);
            if (c == 0) unsafeAtomicAdd(&GC[bprev], (float)cnt);
            acc = 0.f; cnt = 0; bprev = b;
        }
        acc += X[(size_t)n * HID + c];
        ++cnt;
    }
    unsafeAtomicAdd(&GS[(size_t)bprev * HID + c], acc);
    if (c == 0) unsafeAtomicAdd(&GC[bprev], (float)cnt);
}

// Head: one wave per graph; OUTPUT IS FLOAT32.
__global__ void k_head(const float* __restrict__ GS, const float* __restrict__ GC,
                       const void* __restrict__ fcw, const void* __restrict__ fcb,
                       const void* __restrict__ hSw, const void* __restrict__ hSb,
                       const void* __restrict__ hPw, const void* __restrict__ hPb,
                       const void* __restrict__ hNw, const void* __restrict__ hNb,
                       float* __restrict__ out, const int* __restrict__ flags)
{
    const int f32m = flags[0];
    const int g = blockIdx.x;
    const int lane = threadIdx.x;                 // 64 threads
    const float inv = 1.f / fmaxf(GC[g], 1.f);
    const float g0 = GS[(size_t)g * HID + lane]      * inv;
    const float g1 = GS[(size_t)g * HID + 64 + lane] * inv;

    float acc = 0.f;
    for (int k = 0; k < 64; ++k) {
        float gk = __shfl(g0, k, 64);
        acc += gk * ldf(fcw, k * 64 + lane, f32m);
    }
    for (int k = 0; k < 64; ++k) {
        float gk = __shfl(g1, k, 64);
        acc += gk * ldf(fcw, (64 + k) * 64 + lane, f32m);
    }
    float s = fmaxf(acc + ldf(fcb, lane, f32m), 0.f);

    float pS = s * ldf(hSw, lane, f32m);
    float pP = s * ldf(hPw, lane, f32m);
    float pN = s * ldf(hNw, lane, f32m);
#pragma unroll
    for (int off = 32; off; off >>= 1) {
        pS += __shfl_down(pS, off, 64);
        pP += __shfl_down(pP, off, 64);
        pN += __shfl_down(pN, off, 64);
    }
    if (lane == 0) {
        out[g]                = pS + ldf(hSb, 0, f32m);
        out[N_GRAPHS + g]     = pP + ldf(hPb, 0, f32m);
        out[2 * N_GRAPHS + g] = pN + ldf(hNb, 0, f32m);
    }
}

extern "C" void kernel_launch(void* const* d_in, const int* in_sizes, int n_in,
                              void* d_out, int out_size, void* d_ws, size_t ws_size,
                              hipStream_t stream)
{
    const void* x     = d_in[0];
    const void* ei    = d_in[1];
    const void* ea    = d_in[2];
    const void* batch = d_in[3];
    const void* e1w = d_in[4],  *e1b = d_in[5];
    const void* n1w1= d_in[6],  *n1b1= d_in[7];
    const void* n1w2= d_in[8],  *n1b2= d_in[9];
    const void* e2w = d_in[10], *e2b = d_in[11];
    const void* n2w1= d_in[12], *n2b1= d_in[13];
    const void* n2w2= d_in[14], *n2b2= d_in[15];
    const void* fcw = d_in[16], *fcb = d_in[17];
    const void* hSw = d_in[18], *hSb = d_in[19];
    const void* hPw = d_in[20], *hPb = d_in[21];
    const void* hNw = d_in[22], *hNb = d_in[23];

    float* B1  = (float*)d_ws;                         // 6.4M f32 (25.6MB)
    float* B2  = B1 + (size_t)N_NODES * HID;           // 6.4M f32 (25.6MB)
    float* GS  = B2 + (size_t)N_NODES * HID;           // 512*128 f32
    float* GC  = GS + (size_t)N_GRAPHS * HID;          // 512 f32
    int*   FL  = (int*)(GC + N_GRAPHS);                // 4 ints
    int*   PS  = FL + 4;                               // 64 ints (chunk sums)
    int*   OFF = PS + 64;                              // 50000 ints
    int*   CNT = OFF + N_NODES;                        // 50000 ints
    int*   CUR = CNT + N_NODES;                        // 50000 ints
    int2*  ES  = (int2*)(CUR + N_NODES);               // 800000 int2 (6.4MB)
    // total ~58.4 MB

    k_detect<<<1, 64, 0, stream>>>((const unsigned short*)x, (const unsigned int*)ei, FL);
    hipMemsetAsync(GS, 0, (N_GRAPHS * HID + N_GRAPHS) * sizeof(float), stream);
    hipMemsetAsync(CNT, 0, N_NODES * sizeof(int), stream);

    // ---- CSR build (once; shared by both layers) ----
    k_hist   <<<N_EDGES / 256, 256, 0, stream>>>(ei, CNT, FL);
    k_scanA  <<<NCHUNK, SCAN_BLK, 0, stream>>>(CNT, OFF, PS);
    k_scanB  <<<1, 64, 0, stream>>>(PS);
    k_scanC  <<<(N_NODES + 255) / 256, 256, 0, stream>>>(OFF, PS, CUR);
    k_scatter<<<N_EDGES / 256, 256, 0, stream>>>(ei, CUR, ES, FL);

    // ---- Layer 1 ----
    k_edge_csr<<<1024, 512, 0, stream>>>(x, 0, ES, OFF, CNT, ea, e1w, e1b, B1, FL);
    k_mlp_s   <<<512, 1024, 0, stream>>>(B1, n1w1, n1b1, B1, FL);
    k_mlp_s   <<<512, 1024, 0, stream>>>(B1, n1w2, n1b2, B1, FL);     // B1 = h1

    // ---- Layer 2 ----
    k_edge_csr<<<1024, 512, 0, stream>>>(B1, 1, ES, OFF, CNT, ea, e2w, e2b, B2, FL);
    k_mlp_s   <<<512, 1024, 0, stream>>>(B2, n2w1, n2b1, B2, FL);
    k_mlp_s   <<<512, 1024, 0, stream>>>(B2, n2w2, n2b2, B2, FL);     // B2 = h2

    // ---- Pool + heads ----
    k_pool_s<<<(N_NODES + 63) / 64, 128, 0, stream>>>(B2, batch, GS, GC, FL);
    k_head  <<<N_GRAPHS, 64, 0, stream>>>(GS, GC, fcw, fcb, hSw, hSb, hPw, hPb, hNw, hNb,
                                          (float*)d_out, FL);
}

// Round 4
// 1224.131 us; speedup vs baseline: 1.3187x; 1.3187x over previous
//
#include <hip/hip_runtime.h>
#include <hip/hip_bf16.h>

// ---------------------------------------------------------------------------
// GINEConv x2 + mean-pool + 3 heads.  f32 pipeline (correctness anchor).
// KEY FACTS: float inputs = f32, OUTPUT = f32.  Int width runtime-detected.
//
// R5: W float4 in LDS, 8 edges/wave, v_readlane broadcast (995 -> 423us).
// R6: occupancy push: no effect (423 -> 411).  Occupancy counter pinned
//     ~42% regardless of config.
// R7: CSR zero-atomic: REGRESSED (411 -> 561).  Writes dropped 400->25MB
//     with NO speedup => atomics were never the wall (circular reasoning).
//     Random-order ea reads + ES->av dependent chain killed MLP
//     (hbm 1700 -> 588 GB/s at same FETCH).  Reverted.
// R8 (this round): the consistent signature across R1-R3 is dependency-
//     stall latency (per-SIMD VALU issue ~30%, nothing saturated).  Keep
//     R2 flat structure; add software pipelining:
//       - depth-1 prefetch of next chunk's av + indices (ping-pong regs)
//       - x[src] gathers hoisted ABOVE the FMA block (fly under compute)
//       - indices: one exec-masked load (lane<16) + readlane broadcast
//     Pool: 16 nodes/block + readlane batch ids + full unroll.
// ---------------------------------------------------------------------------

typedef __bf16 bf16_t;

#define N_NODES   50000
#define N_EDGES   800000
#define N_GRAPHS  512
#define HID       128
#define EIN       64
#define PNODES    16            // nodes per pool block (50000/16 = 3125 exact)

// broadcast lane l of v across the wave via v_readlane (no LDS traffic)
#define RL(v, l)  __int_as_float(__builtin_amdgcn_readlane(__float_as_int(v), (l)))
#define RLI(v, l) __builtin_amdgcn_readlane((v), (l))

__device__ __forceinline__ float ldf(const void* p, size_t i, int f32m) {
    return f32m ? ((const float*)p)[i] : (float)((const bf16_t*)p)[i];
}
__device__ __forceinline__ int ldi(const void* p, size_t i, int i64m) {
    return i64m ? (int)((const long long*)p)[i] : ((const int*)p)[i];
}

// flags[0]=1 if floats are f32; flags[1]=1 if ints are i64.
__global__ void k_detect(const unsigned short* __restrict__ xw,
                         const unsigned int*   __restrict__ eiw,
                         int* __restrict__ flags)
{
    if (threadIdx.x == 0 && blockIdx.x == 0) {
        int sane = 0;
        for (int i = 0; i < 256; ++i) {
            int e = (xw[i] >> 7) & 0xFF;
            if (e >= 100 && e <= 150) ++sane;    // bf16 N(0,1): ~256; f32: ~154
        }
        flags[0] = (sane < 220) ? 1 : 0;
        int nzhigh = 0;
        for (int i = 0; i < 256; ++i)
            if (eiw[2*i + 1] != 0) ++nzhigh;     // i64 ids < 2^32: high words 0
        flags[1] = (nzhigh == 0) ? 1 : 0;
    }
}

// convert x -> f32 workspace, float4 path when already f32
__global__ void k_cvt4(const void* __restrict__ x, float* __restrict__ dst,
                       const int* __restrict__ flags) {
    const int f32m = flags[0];
    size_t i = (size_t)blockIdx.x * 256 + threadIdx.x;     // float4 index
    if (f32m) {
        ((float4*)dst)[i] = ((const float4*)x)[i];
    } else {
        const bf16_t* s = (const bf16_t*)x;
        float4 v;
        v.x = (float)s[4*i+0]; v.y = (float)s[4*i+1];
        v.z = (float)s[4*i+2]; v.w = (float)s[4*i+3];
        ((float4*)dst)[i] = v;
    }
}

// ---------------------------------------------------------------------------
// Fused edge kernel, software-pipelined.  Wave owns 8 edges per step.
//   e = ea@W + eb (readlane broadcast, W float4 in LDS); m = relu(x_src + e);
//   atomicAdd into ag[dst].
// Pipeline per iteration:
//   issue next chunk's av+idx loads -> compute current src/dst (readlane)
//   -> issue current x-gathers -> 16x k4 FMA block (hides all loads)
//   -> combine + atomics -> ping-pong regs.
// ---------------------------------------------------------------------------
__global__ __launch_bounds__(512) void k_edge_s(
        const void* __restrict__ Xg, int xg_ws,   // xg_ws=1: Xg is f32 workspace
        const void* __restrict__ ei,
        const void* __restrict__ ea,
        const void* __restrict__ ew,
        const void* __restrict__ eb,
        float*      __restrict__ ag,
        const int*  __restrict__ flags)
{
    __shared__ float4 Wq[16 * 128];               // 32 KB
    __shared__ float  ebs[HID];
    const int f32m = flags[0];
    const int i64m = flags[1];
    const int xgf  = xg_ws ? 1 : f32m;

    for (int i = threadIdx.x; i < 16 * 128; i += 512) {
        int k4 = i >> 7, c = i & 127;
        float4 w;
        w.x = ldf(ew, (size_t)(4*k4+0)*HID + c, f32m);
        w.y = ldf(ew, (size_t)(4*k4+1)*HID + c, f32m);
        w.z = ldf(ew, (size_t)(4*k4+2)*HID + c, f32m);
        w.w = ldf(ew, (size_t)(4*k4+3)*HID + c, f32m);
        Wq[i] = w;
    }
    for (int i = threadIdx.x; i < HID; i += 512) ebs[i] = ldf(eb, i, f32m);
    __syncthreads();

    const int lane = threadIdx.x & 63;
    const int wid  = (blockIdx.x * 512 + threadIdx.x) >> 6;
    const int nw   = gridDim.x * 8;
    const int ngrp = N_EDGES / 8;                 // 100000 exact
    const float eb0 = ebs[lane], eb1 = ebs[64 + lane];

    // lane<16 composite index load: lanes 0-7 -> src, lanes 8-15 -> dst
    auto LOADIDX = [&](int e0) -> int {
        int v = 0;
        if (lane < 16) {
            size_t idx = (lane < 8) ? (size_t)(e0 + lane)
                                    : (size_t)N_EDGES + (e0 + lane - 8);
            v = ldi(ei, idx, i64m);
        }
        return v;
    };

    int g = wid;
    if (g < ngrp) {
        // prologue: load chunk g
        float avA[8]; int vvA;
        {
            const int e0 = g * 8;
            vvA = LOADIDX(e0);
#pragma unroll
            for (int i = 0; i < 8; ++i)
                avA[i] = ldf(ea, (size_t)(e0+i) * EIN + lane, f32m);
        }

        while (true) {
            // ---- prefetch next chunk (independent of everything below) ----
            const int gB = g + nw;
            const bool hasB = (gB < ngrp);
            float avB[8]; int vvB = 0;
            if (hasB) {
                const int e0B = gB * 8;
                vvB = LOADIDX(e0B);
#pragma unroll
                for (int i = 0; i < 8; ++i)
                    avB[i] = ldf(ea, (size_t)(e0B+i) * EIN + lane, f32m);
            }

            // ---- current chunk: indices via readlane (VALU only) ----
            int src[8], dst[8];
#pragma unroll
            for (int i = 0; i < 8; ++i) {
                src[i] = RLI(vvA, i);
                dst[i] = RLI(vvA, 8 + i);
            }
            // issue x-gathers now; consumed after the FMA block
            float x0[8], x1[8];
#pragma unroll
            for (int i = 0; i < 8; ++i) {
                x0[i] = ldf(Xg, (size_t)src[i] * HID + lane,      xgf);
                x1[i] = ldf(Xg, (size_t)src[i] * HID + 64 + lane, xgf);
            }

            float acc0[8], acc1[8];
#pragma unroll
            for (int i = 0; i < 8; ++i) { acc0[i] = 0.f; acc1[i] = 0.f; }

#pragma unroll 4
            for (int k4 = 0; k4 < 16; ++k4) {
                float4 w0 = Wq[k4 * 128 + lane];
                float4 w1 = Wq[k4 * 128 + 64 + lane];
#pragma unroll
                for (int i = 0; i < 8; ++i) {
                    float a0 = RL(avA[i], 4*k4+0);
                    float a1 = RL(avA[i], 4*k4+1);
                    float a2 = RL(avA[i], 4*k4+2);
                    float a3 = RL(avA[i], 4*k4+3);
                    // strict ascending-k association (matches prior rounds)
                    acc0[i] = fmaf(a3, w0.w, fmaf(a2, w0.z, fmaf(a1, w0.y, fmaf(a0, w0.x, acc0[i]))));
                    acc1[i] = fmaf(a3, w1.w, fmaf(a2, w1.z, fmaf(a1, w1.y, fmaf(a0, w1.x, acc1[i]))));
                }
            }

#pragma unroll
            for (int i = 0; i < 8; ++i) {
                float v0 = fmaxf(x0[i] + acc0[i] + eb0, 0.f);
                float v1 = fmaxf(x1[i] + acc1[i] + eb1, 0.f);
                unsafeAtomicAdd(ag + (size_t)dst[i] * HID + lane,      v0);
                unsafeAtomicAdd(ag + (size_t)dst[i] * HID + 64 + lane, v1);
            }

            if (!hasB) break;
            g = gB;
            vvA = vvB;
#pragma unroll
            for (int i = 0; i < 8; ++i) avA[i] = avB[i];
        }
    }
}

// ---------------------------------------------------------------------------
// Node MLP: Out[n] = relu(A[n] @ W + b).  8 nodes per wave, W float4 in LDS.
// 1024 thr/block, 64KB LDS -> 2 blocks/CU = 32 waves/CU.
// In-place safe: all 8 rows consumed into registers before any write.
// Out2 (optional): duplicate store, folds the inter-layer copy.
// ---------------------------------------------------------------------------
__global__ __launch_bounds__(1024) void k_mlp_s(
        const float* __restrict__ A,
        const void*  __restrict__ W,
        const void*  __restrict__ bias,
        float*       __restrict__ Out,
        float*       __restrict__ Out2,
        const int*   __restrict__ flags)
{
    __shared__ float4 Wq[32 * 128];               // 64 KB
    const int f32m = flags[0];
    for (int i = threadIdx.x; i < 32 * 128; i += 1024) {
        int k4 = i >> 7, c = i & 127;
        float4 w;
        w.x = ldf(W, (size_t)(4*k4+0)*HID + c, f32m);
        w.y = ldf(W, (size_t)(4*k4+1)*HID + c, f32m);
        w.z = ldf(W, (size_t)(4*k4+2)*HID + c, f32m);
        w.w = ldf(W, (size_t)(4*k4+3)*HID + c, f32m);
        Wq[i] = w;
    }
    __syncthreads();

    const int lane = threadIdx.x & 63;
    const int wid  = (blockIdx.x * 1024 + threadIdx.x) >> 6;
    const int nw   = gridDim.x * 16;
    const float b0 = ldf(bias, lane,      f32m);
    const float b1 = ldf(bias, 64 + lane, f32m);
    const int ngrp = N_NODES / 8;                 // 6250 exact

    for (int g = wid; g < ngrp; g += nw) {
        const int n0 = g * 8;
        float alo[8], ahi[8], acc0[8], acc1[8];
#pragma unroll
        for (int i = 0; i < 8; ++i) {
            alo[i] = A[(size_t)(n0+i) * HID + lane];
            ahi[i] = A[(size_t)(n0+i) * HID + 64 + lane];
            acc0[i] = b0; acc1[i] = b1;
        }
#pragma unroll 4
        for (int k4 = 0; k4 < 16; ++k4) {
            float4 w0 = Wq[k4 * 128 + lane];
            float4 w1 = Wq[k4 * 128 + 64 + lane];
#pragma unroll
            for (int i = 0; i < 8; ++i) {
                float a0 = RL(alo[i], 4*k4+0);
                float a1 = RL(alo[i], 4*k4+1);
                float a2 = RL(alo[i], 4*k4+2);
                float a3 = RL(alo[i], 4*k4+3);
                acc0[i] = fmaf(a3, w0.w, fmaf(a2, w0.z, fmaf(a1, w0.y, fmaf(a0, w0.x, acc0[i]))));
                acc1[i] = fmaf(a3, w1.w, fmaf(a2, w1.z, fmaf(a1, w1.y, fmaf(a0, w1.x, acc1[i]))));
            }
        }
#pragma unroll 4
        for (int k4 = 16; k4 < 32; ++k4) {
            float4 w0 = Wq[k4 * 128 + lane];
            float4 w1 = Wq[k4 * 128 + 64 + lane];
#pragma unroll
            for (int i = 0; i < 8; ++i) {
                float a0 = RL(ahi[i], 4*k4+0 - 64);
                float a1 = RL(ahi[i], 4*k4+1 - 64);
                float a2 = RL(ahi[i], 4*k4+2 - 64);
                float a3 = RL(ahi[i], 4*k4+3 - 64);
                acc0[i] = fmaf(a3, w0.w, fmaf(a2, w0.z, fmaf(a1, w0.y, fmaf(a0, w0.x, acc0[i]))));
                acc1[i] = fmaf(a3, w1.w, fmaf(a2, w1.z, fmaf(a1, w1.y, fmaf(a0, w1.x, acc1[i]))));
            }
        }
#pragma unroll
        for (int i = 0; i < 8; ++i) {
            float v0 = fmaxf(acc0[i], 0.f);
            float v1 = fmaxf(acc1[i], 0.f);
            Out[(size_t)(n0+i) * HID + lane]      = v0;
            Out[(size_t)(n0+i) * HID + 64 + lane] = v1;
            if (Out2) {
                Out2[(size_t)(n0+i) * HID + lane]      = v0;
                Out2[(size_t)(n0+i) * HID + 64 + lane] = v1;
            }
        }
    }
}

// ---------------------------------------------------------------------------
// Pool: batch is SORTED -> run-length accumulate, flush at boundaries.
// 16 nodes/block (3125 blocks), batch ids via masked load + readlane,
// fully unrolled n-loop (order-preserving; loads batched by compiler).
// ---------------------------------------------------------------------------
__global__ void k_pool_s(const float* __restrict__ X, const void* __restrict__ batch,
                         float* __restrict__ GS, float* __restrict__ GC,
                         const int* __restrict__ flags)
{
    const int i64m = flags[1];
    const int c  = threadIdx.x;                   // 0..127 (2 waves)
    const int tl = threadIdx.x & 63;
    const int n0 = blockIdx.x * PNODES;           // 3125*16 = 50000 exact

    int bv = (tl < PNODES) ? ldi(batch, n0 + tl, i64m) : 0;

    int bprev = RLI(bv, 0);
    float acc = 0.f;
    int   cnt = 0;
#pragma unroll
    for (int j = 0; j < PNODES; ++j) {
        int b = RLI(bv, j);
        if (b != bprev) {                         // wave-uniform branch
            unsafeAtomicAdd(&GS[(size_t)bprev * HID + c], acc);
            if (c == 0) unsafeAtomicAdd(&GC[bprev], (float)cnt);
            acc = 0.f; cnt = 0; bprev = b;
        }
        acc += X[(size_t)(n0 + j) * HID + c];
        ++cnt;
    }
    unsafeAtomicAdd(&GS[(size_t)bprev * HID + c], acc);
    if (c == 0) unsafeAtomicAdd(&GC[bprev], (float)cnt);
}

// Head: one wave per graph; OUTPUT IS FLOAT32.
__global__ void k_head(const float* __restrict__ GS, const float* __restrict__ GC,
                       const void* __restrict__ fcw, const void* __restrict__ fcb,
                       const void* __restrict__ hSw, const void* __restrict__ hSb,
                       const void* __restrict__ hPw, const void* __restrict__ hPb,
                       const void* __restrict__ hNw, const void* __restrict__ hNb,
                       float* __restrict__ out, const int* __restrict__ flags)
{
    const int f32m = flags[0];
    const int g = blockIdx.x;
    const int lane = threadIdx.x;                 // 64 threads
    const float inv = 1.f / fmaxf(GC[g], 1.f);
    const float g0 = GS[(size_t)g * HID + lane]      * inv;
    const float g1 = GS[(size_t)g * HID + 64 + lane] * inv;

    float acc = 0.f;
    for (int k = 0; k < 64; ++k) {
        float gk = __shfl(g0, k, 64);
        acc += gk * ldf(fcw, k * 64 + lane, f32m);
    }
    for (int k = 0; k < 64; ++k) {
        float gk = __shfl(g1, k, 64);
        acc += gk * ldf(fcw, (64 + k) * 64 + lane, f32m);
    }
    float s = fmaxf(acc + ldf(fcb, lane, f32m), 0.f);

    float pS = s * ldf(hSw, lane, f32m);
    float pP = s * ldf(hPw, lane, f32m);
    float pN = s * ldf(hNw, lane, f32m);
#pragma unroll
    for (int off = 32; off; off >>= 1) {
        pS += __shfl_down(pS, off, 64);
        pP += __shfl_down(pP, off, 64);
        pN += __shfl_down(pN, off, 64);
    }
    if (lane == 0) {
        out[g]                = pS + ldf(hSb, 0, f32m);
        out[N_GRAPHS + g]     = pP + ldf(hPb, 0, f32m);
        out[2 * N_GRAPHS + g] = pN + ldf(hNb, 0, f32m);
    }
}

extern "C" void kernel_launch(void* const* d_in, const int* in_sizes, int n_in,
                              void* d_out, int out_size, void* d_ws, size_t ws_size,
                              hipStream_t stream)
{
    const void* x     = d_in[0];
    const void* ei    = d_in[1];
    const void* ea    = d_in[2];
    const void* batch = d_in[3];
    const void* e1w = d_in[4],  *e1b = d_in[5];
    const void* n1w1= d_in[6],  *n1b1= d_in[7];
    const void* n1w2= d_in[8],  *n1b2= d_in[9];
    const void* e2w = d_in[10], *e2b = d_in[11];
    const void* n2w1= d_in[12], *n2b1= d_in[13];
    const void* n2w2= d_in[14], *n2b2= d_in[15];
    const void* fcw = d_in[16], *fcb = d_in[17];
    const void* hSw = d_in[18], *hSb = d_in[19];
    const void* hPw = d_in[20], *hPb = d_in[21];
    const void* hNw = d_in[22], *hNb = d_in[23];

    float* B1 = (float*)d_ws;                          // 6.4M f32
    float* B2 = B1 + (size_t)N_NODES * HID;            // 6.4M f32
    float* GS = B2 + (size_t)N_NODES * HID;            // 512*128 f32
    float* GC = GS + (size_t)N_GRAPHS * HID;           // 512 f32
    int*   FL = (int*)(GC + N_GRAPHS);                 // 2 ints

    k_detect<<<1, 64, 0, stream>>>((const unsigned short*)x, (const unsigned int*)ei, FL);
    hipMemsetAsync(GS, 0, (N_GRAPHS * HID + N_GRAPHS) * sizeof(float), stream);

    const int NV4_BLKS = (N_NODES * HID / 4) / 256;    // 6250 (exact)

    // Layer 1
    k_cvt4  <<<NV4_BLKS, 256, 0, stream>>>(x, B1, FL);
    k_edge_s<<<2048, 512, 0, stream>>>(x, 0, ei, ea, e1w, e1b, B1, FL);
    k_mlp_s <<<512, 1024, 0, stream>>>(B1, n1w1, n1b1, B1, nullptr, FL);
    k_mlp_s <<<512, 1024, 0, stream>>>(B1, n1w2, n1b2, B1, B2, FL);   // B1 = h1, B2 = copy

    // Layer 2
    k_edge_s<<<2048, 512, 0, stream>>>(B1, 1, ei, ea, e2w, e2b, B2, FL);
    k_mlp_s <<<512, 1024, 0, stream>>>(B2, n2w1, n2b1, B2, nullptr, FL);
    k_mlp_s <<<512, 1024, 0, stream>>>(B2, n2w2, n2b2, B2, nullptr, FL);  // B2 = h2

    // Pool + heads
    k_pool_s<<<N_NODES / PNODES, 128, 0, stream>>>(B2, batch, GS, GC, FL);
    k_head  <<<N_GRAPHS, 64, 0, stream>>>(GS, GC, fcw, fcb, hSw, hSb, hPw, hPb, hNw, hNb,
                                          (float*)d_out, FL);
}